// Round 6
// baseline (553.961 us; speedup 1.0000x reference)
//
#include <hip/hip_runtime.h>

#define NN 4096
#define BN 32768

typedef __attribute__((ext_vector_type(8))) short short8;
typedef __attribute__((ext_vector_type(4))) float f32x4;

__device__ __forceinline__ float sigmoidf_(float x){ return 1.f/(1.f+__expf(-x)); }
__device__ __forceinline__ unsigned short bfr(float f){
    unsigned int u = __float_as_uint(f);
    u += 0x7FFFu + ((u>>16)&1u);
    return (unsigned short)(u>>16);
}
__device__ __forceinline__ float b2f(unsigned short h){
    return __uint_as_float(((unsigned int)h)<<16);
}

// ---- prep: As/Ad, cE, AsAdT[16][64] bf16, WT2 hi/lo [64 j][256 khh] bf16 ----
// WT2[j][hh*64+k] = W_gat[k][hh*64+j]
__global__ void prep_kernel(const float* __restrict__ W_gat,
                            const float* __restrict__ att_src,
                            const float* __restrict__ att_dst,
                            const float* __restrict__ W_edge,
                            const float* __restrict__ att_edge,
                            float* __restrict__ As, float* __restrict__ Ad,
                            float* __restrict__ cE,
                            unsigned short* __restrict__ AsAdT,
                            unsigned short* __restrict__ WT2h,
                            unsigned short* __restrict__ WT2l)
{
    int t = threadIdx.x;          // 256
    int i = t >> 2, hh = t & 3;   // t = k*4+h
    float s = 0.f, d = 0.f;
    for (int j = 0; j < 64; j++){
        float w = W_gat[i*256 + hh*64 + j];
        s += w * att_src[hh*64 + j];
        d += w * att_dst[hh*64 + j];
    }
    As[t] = s;
    Ad[t] = d;
    if (t < 12){
        int e = t >> 2, h2 = t & 3;
        float cc = 0.f;
        for (int k = 0; k < 64; k++)
            cc += W_edge[e*256 + h2*64 + k] * att_edge[h2*64 + k];
        cE[h2*3 + e] = cc;
    }
    __syncthreads();
    if (t < 16){
        for (int k = 0; k < 64; k++){
            float v = (t < 4) ? As[k*4 + t] : (t < 8 ? Ad[k*4 + (t-4)] : 0.f);
            AsAdT[t*64 + k] = bfr(v);
        }
    }
    {
        int j = t >> 2, q = t & 3;
        for (int k = 0; k < 64; k++){
            float wv = W_gat[k*256 + q*64 + j];
            unsigned short hi = bfr(wv);
            WT2h[j*256 + q*64 + k] = hi;
            WT2l[j*256 + q*64 + k] = bfr(wv - b2f(hi));
        }
    }
}

// ---- encoder: block = 64 consecutive nodes, lane = node; node-major H + HA ----
__global__ __launch_bounds__(256) void enc_kernel(
    const float* __restrict__ x,
    const float* __restrict__ W1, const float* __restrict__ b1,
    const float* __restrict__ W2, const float* __restrict__ b2,
    float* __restrict__ H, float* __restrict__ HA)
{
    __shared__ __align__(16) float sm[5168];
    float* xT  = sm;          // [12][68]
    float* t1  = sm + 816;    // [64][68]

    int t = threadIdx.x;
    int w = __builtin_amdgcn_readfirstlane(t >> 6);
    int lane = t & 63;
    int n0 = blockIdx.x * 64;
    int b = n0 >> 12;
    int cell0 = n0 & 4095;

    for (int e = t; e < 12*64; e += 256){
        int c = e >> 6, u = e & 63;
        xT[c*68 + u] = x[b*(12*NN) + c*NN + cell0 + u];
    }
    __syncthreads();

    #pragma unroll
    for (int jj = 0; jj < 16; jj++){
        int j = w*16 + jj;
        float a = b1[j];
        #pragma unroll
        for (int c = 0; c < 12; c++)
            a += xT[c*68 + lane] * W1[c*64 + j];
        t1[j*68 + lane] = a * sigmoidf_(a);
    }
    __syncthreads();

    float hk[16];
    #pragma unroll
    for (int kk = 0; kk < 16; kk++) hk[kk] = b2[w*16 + kk];
    for (int j = 0; j < 64; j++){
        float v = t1[j*68 + lane];
        #pragma unroll
        for (int kk = 0; kk < 16; kk++)
            hk[kk] += v * W2[j*64 + w*16 + kk];
    }
    int hb = (n0 + lane)*64 + w*16;
    #pragma unroll
    for (int j4 = 0; j4 < 4; j4++){
        float4 v = make_float4(hk[4*j4+0], hk[4*j4+1], hk[4*j4+2], hk[4*j4+3]);
        *(float4*)&H[hb + 4*j4]  = v;
        *(float4*)&HA[hb + 4*j4] = v;
    }
}

// ================== full-MFMA f(): one RK4 stage ==================
// block = 8x8 tile + halo-1 (10x10); 4 waves; lane-e mapping; XOR-swizzled LDS.
__global__ __launch_bounds__(256,2) void f_kernel(
    const float* __restrict__ HINc,        // stage input [BN][64] f32
    const float* __restrict__ x,
    const float* __restrict__ CCE,
    const unsigned short* __restrict__ AsAdT,
    const unsigned short* __restrict__ WT2h, const unsigned short* __restrict__ WT2l,
    const float* __restrict__ b_gat, const float* __restrict__ g_f, const float* __restrict__ bt_f,
    float* __restrict__ H, float* __restrict__ HOUT, float* __restrict__ ACC,
    int stage)
{
    __shared__ __align__(16) char smem[69632];
    // hA_T  : [64 k][128 m] bf16 swz   @ 0      (16384 B)
    // aM    : [64 e][128 m] bf16 swz   @ 16384  (16384 B)
    // gL    : [64 e][256 khh] bf16 swz @ 32768  (32768 B)
    float* as2 = (float*)(smem + 65536);   // [112][4]
    float* ad2 = (float*)(smem + 67328);   // [112][4]
    float* x0h = (float*)(smem + 69120);   // [128]

    int t = threadIdx.x;
    int w = __builtin_amdgcn_readfirstlane(t >> 6);
    int lane = t & 63;
    int l15 = lane & 15, lg = lane >> 4;
    int blk = blockIdx.x;
    int b = blk & 7, tile = blk >> 3;      // batch pinned to XCD
    int tr = tile >> 3, tc = tile & 7;
    int r0 = tr*8 - 1, c0 = tc*8 - 1;
    int nb = b*NN;
    int xb = b*(12*NN);

    const int DYI[8] = {-1,-1,-1,0,0,1,1,1};
    const int DXI[8] = {-1,0,1,-1,1,-1,0,1};
    const float s2c = 0.70710678f;
    const float DXN[8] = {-s2c,0.f,s2c,-1.f,1.f,-s2c,0.f,s2c};
    const float DYN[8] = {-s2c,-1.f,-s2c,0.f,0.f,s2c,1.f,s2c};

    // ---- phase 1: stage halo into hA_T (swz) + x0h; zero aM ----
    for (int u = t; u < 1024; u += 256)
        *(float4*)(smem + 16384 + u*16) = make_float4(0.f,0.f,0.f,0.f);
    for (int u = t; u < 2048; u += 256){
        int m = u & 127, k4 = u >> 7;
        int k0 = k4*4;
        float4 v = make_float4(0.f,0.f,0.f,0.f);
        if (m < 100){
            int hr = m/10, hc = m - hr*10;
            int r = min(63,max(0,r0+hr)), c = min(63,max(0,c0+hc));
            v = *(const float4*)&HINc[(long)(nb + r*64 + c)*64 + k0];
            if (k4 == 0) x0h[m] = x[xb + r*64 + c];
        } else if (k4 == 0) x0h[m] = 0.f;
        *(unsigned short*)(smem + (((k0+0)*256 + m*2) ^ (((k0+0)&7)<<4))) = bfr(v.x);
        *(unsigned short*)(smem + (((k0+1)*256 + m*2) ^ (((k0+1)&7)<<4))) = bfr(v.y);
        *(unsigned short*)(smem + (((k0+2)*256 + m*2) ^ (((k0+2)&7)<<4))) = bfr(v.z);
        *(unsigned short*)(smem + (((k0+3)*256 + m*2) ^ (((k0+3)&7)<<4))) = bfr(v.w);
    }
    __syncthreads();

    // ---- phase 2: as/ad via MFMA: C[16 rows=(as0-3,ad0-3,pad)][m] ----
    for (int nt = w; nt < 7; nt += 4){
        int m = nt*16 + l15;
        int hr = m/10, hc = m - hr*10;
        int r = min(63,max(0,r0+hr)), c = min(63,max(0,c0+hc));
        const float* hp = &HINc[(long)(nb + r*64 + c)*64];
        f32x4 acc = {0.f,0.f,0.f,0.f};
        #pragma unroll
        for (int kt = 0; kt < 2; kt++){
            int k = kt*32 + lg*8;
            short8 afr = *(const short8*)&AsAdT[l15*64 + k];
            float4 f0 = *(const float4*)&hp[k];
            float4 f1 = *(const float4*)&hp[k+4];
            short8 bfrg;
            bfrg[0]=(short)bfr(f0.x); bfrg[1]=(short)bfr(f0.y);
            bfrg[2]=(short)bfr(f0.z); bfrg[3]=(short)bfr(f0.w);
            bfrg[4]=(short)bfr(f1.x); bfrg[5]=(short)bfr(f1.y);
            bfrg[6]=(short)bfr(f1.z); bfrg[7]=(short)bfr(f1.w);
            acc = __builtin_amdgcn_mfma_f32_16x16x32_bf16(afr, bfrg, acc, 0,0,0);
        }
        if (lg == 0)      *(float4*)&as2[m*4] = *(float4*)&acc;
        else if (lg == 1) *(float4*)&ad2[m*4] = *(float4*)&acc;
    }
    __syncthreads();

    // ---- phase 3: alpha (thread = (e = lane, head = w)) ----
    int e = lane, hh = w;
    int er = e >> 3, ec = e & 7;
    int gr = tr*8 + er, gc = tc*8 + ec;
    int me = (er+1)*10 + (ec+1);
    float al[8]; int hmr[8];
    {
        float adv = ad2[me*4 + hh];
        float x0n = x0h[me];
        float ce0 = CCE[hh*3+0], ce1 = CCE[hh*3+1], ce2 = CCE[hh*3+2];
        float mx = -1e30f;
        #pragma unroll
        for (int o = 0; o < 8; o++){
            int mr = gr - DYI[o], mc = gc - DXI[o];
            bool vld = (mr>=0)&&(mr<64)&&(mc>=0)&&(mc<64);
            int hm = me - DYI[o]*10 - DXI[o];
            hmr[o] = hm;
            float a = as2[hm*4+hh] + adv + ce0*DXN[o] + ce1*DYN[o]
                    + ce2*(x0n - x0h[hm]);
            a = (a >= 0.f) ? a : 0.2f*a;
            al[o] = vld ? a : -1e30f;
            mx = fmaxf(mx, al[o]);
        }
        float z = 0.f;
        #pragma unroll
        for (int o = 0; o < 8; o++){
            float p = (al[o] > -1e29f) ? __expf(al[o]-mx) : 0.f;
            al[o] = p; z += p;
        }
        float zi = 1.f/(z + 1e-16f);
        #pragma unroll
        for (int o = 0; o < 8; o++) al[o] *= zi;
    }

    // ---- phase 4: per head: scatter alpha row, stencil MFMA -> gL ----
    for (int h2 = 0; h2 < 4; ++h2){
        if (hh == h2){
            #pragma unroll
            for (int o = 0; o < 8; o++)
                *(unsigned short*)(smem + 16384 + ((e*256 + hmr[o]*2) ^ ((e&7)<<4)))
                    = bfr(al[o]);
        }
        __syncthreads();
        f32x4 sacc[4];
        #pragma unroll
        for (int nt = 0; nt < 4; nt++) sacc[nt] = (f32x4){0.f,0.f,0.f,0.f};
        #pragma unroll
        for (int kt = 0; kt < 4; kt++){
            int row = w*16 + l15;
            short8 afr = *(const short8*)(smem + 16384 +
                ((row*256 + (kt*32+lg*8)*2) ^ ((row&7)<<4)));
            #pragma unroll
            for (int nt = 0; nt < 4; nt++){
                int k2 = nt*16 + l15;
                short8 bfrg = *(const short8*)(smem +
                    ((k2*256 + (kt*32+lg*8)*2) ^ ((k2&7)<<4)));
                sacc[nt] = __builtin_amdgcn_mfma_f32_16x16x32_bf16(afr, bfrg, sacc[nt], 0,0,0);
            }
        }
        #pragma unroll
        for (int nt = 0; nt < 4; nt++){
            #pragma unroll
            for (int reg = 0; reg < 4; reg++){
                int e2 = w*16 + lg*4 + reg;
                int col = h2*64 + nt*16 + l15;
                *(unsigned short*)(smem + 32768 + ((e2*512 + col*2) ^ ((e2&7)<<4)))
                    = bfr(sacc[nt][reg]);
            }
        }
        __syncthreads();
    }

    // ---- phase 5: stacked GEMM out[e][j] = gL @ WT2 (hi+lo) ----
    f32x4 oacc[4];
    #pragma unroll
    for (int nt = 0; nt < 4; nt++) oacc[nt] = (f32x4){0.f,0.f,0.f,0.f};
    #pragma unroll
    for (int half = 0; half < 2; half++){
        const unsigned short* Wt = half ? WT2l : WT2h;
        #pragma unroll
        for (int kt = 0; kt < 8; kt++){
            int e2 = w*16 + l15;
            short8 afr = *(const short8*)(smem + 32768 +
                ((e2*512 + (kt*32+lg*8)*2) ^ ((e2&7)<<4)));
            #pragma unroll
            for (int nt = 0; nt < 4; nt++){
                short8 bfrg = *(const short8*)&Wt[(nt*16+l15)*256 + kt*32 + lg*8];
                oacc[nt] = __builtin_amdgcn_mfma_f32_16x16x32_bf16(afr, bfrg, oacc[nt], 0,0,0);
            }
        }
    }

    // ---- phase 6: epilogue: LN (16-lane shfl) + silu + RK4 ----
    float bg[4], gf[4], bf[4];
    #pragma unroll
    for (int nt = 0; nt < 4; nt++){
        int j = nt*16 + l15;
        bg[nt] = b_gat[j]; gf[nt] = g_f[j]; bf[nt] = bt_f[j];
    }
    #pragma unroll
    for (int reg = 0; reg < 4; reg++){
        int e2 = w*16 + lg*4 + reg;
        float vv[4];
        float s1 = 0.f, s2 = 0.f;
        #pragma unroll
        for (int nt = 0; nt < 4; nt++){
            float v = oacc[nt][reg]*0.25f + bg[nt];
            vv[nt] = v; s1 += v; s2 += v*v;
        }
        s1 += __shfl_xor(s1,1); s2 += __shfl_xor(s2,1);
        s1 += __shfl_xor(s1,2); s2 += __shfl_xor(s2,2);
        s1 += __shfl_xor(s1,4); s2 += __shfl_xor(s2,4);
        s1 += __shfl_xor(s1,8); s2 += __shfl_xor(s2,8);
        float mean = s1*(1.f/64.f);
        float var  = s2*(1.f/64.f) - mean*mean;
        float rstd = rsqrtf(fmaxf(var,0.f) + 1e-5f);
        int r2 = e2 >> 3, c2 = e2 & 7;
        long gn = nb + (tr*8 + r2)*64 + (tc*8 + c2);
        #pragma unroll
        for (int nt = 0; nt < 4; nt++){
            int j = nt*16 + l15;
            float y = (vv[nt]-mean)*rstd*gf[nt] + bf[nt];
            float kv = y * sigmoidf_(y);
            long idx = gn*64 + j;
            float hold = H[idx];
            float hn;
            if (stage == 0){
                ACC[idx] = kv;                 hn = hold + 0.125f*kv;
            } else if (stage == 1){
                ACC[idx] += 2.f*kv;            hn = hold + 0.125f*kv;
            } else if (stage == 2){
                ACC[idx] += 2.f*kv;            hn = hold + 0.25f*kv;
            } else {
                hn = hold + (0.25f/6.f)*(ACC[idx] + kv);
                H[idx] = hn;
            }
            HOUT[idx] = hn;
        }
    }
}

// ---- head: LN + MLP + fire override ----
__global__ __launch_bounds__(256) void head_kernel(
    const float* __restrict__ H, const float* __restrict__ x,
    const float* __restrict__ g_h, const float* __restrict__ bt_h,
    const float* __restrict__ Wh1, const float* __restrict__ bh1,
    const float* __restrict__ Wh2, const float* __restrict__ bh2,
    float* __restrict__ out)
{
    __shared__ __align__(16) float sm[4624];
    float* hT = sm;          // [64][68]
    float* pl = sm + 4352;   // [4][68]

    int t = threadIdx.x;
    int w = __builtin_amdgcn_readfirstlane(t >> 6);
    int lane = t & 63;
    int n0 = blockIdx.x * 64;
    int b = n0 >> 12;
    int cell0 = n0 & 4095;

    for (int e = t; e < 4096; e += 256){
        int n = e >> 6, j = e & 63;
        hT[j*68 + n] = H[(n0+n)*64 + j];
    }
    __syncthreads();

    float s1 = 0.f, s2 = 0.f;
    for (int j = 0; j < 64; j++){
        float v = hT[j*68 + lane];
        s1 += v; s2 += v*v;
    }
    float mean = s1*(1.f/64.f);
    float var  = s2*(1.f/64.f) - mean*mean;
    float rstd = rsqrtf(fmaxf(var, 0.f) + 1e-5f);

    float acc[16];
    #pragma unroll
    for (int kk = 0; kk < 16; kk++) acc[kk] = bh1[w*16 + kk];
    for (int j = 0; j < 64; j++){
        float v = (hT[j*68 + lane] - mean)*rstd*g_h[j] + bt_h[j];
        #pragma unroll
        for (int kk = 0; kk < 16; kk++)
            acc[kk] += v * Wh1[j*64 + w*16 + kk];
    }
    float plg = 0.f;
    #pragma unroll
    for (int kk = 0; kk < 16; kk++){
        float a = acc[kk];
        plg += (a * sigmoidf_(a)) * Wh2[w*16 + kk];
    }
    pl[w*68 + lane] = plg;
    __syncthreads();
    if (t < 64){
        float lgt = pl[0*68+t] + pl[1*68+t] + pl[2*68+t] + pl[3*68+t] + bh2[0];
        float fire = x[b*(12*NN) + cell0 + t];
        out[n0 + t] = (fire > 0.5f) ? fmaxf(lgt, 6.f) : lgt;
    }
}

extern "C" void kernel_launch(void* const* d_in, const int* in_sizes, int n_in,
                              void* d_out, int out_size, void* d_ws, size_t ws_size,
                              hipStream_t stream)
{
    const float* x       = (const float*)d_in[0];
    const float* W_enc1  = (const float*)d_in[3];
    const float* b_enc1  = (const float*)d_in[4];
    const float* W_enc2  = (const float*)d_in[5];
    const float* b_enc2  = (const float*)d_in[6];
    const float* W_gat   = (const float*)d_in[7];
    const float* att_src = (const float*)d_in[8];
    const float* att_dst = (const float*)d_in[9];
    const float* W_edge  = (const float*)d_in[10];
    const float* att_edge= (const float*)d_in[11];
    const float* b_gat   = (const float*)d_in[12];
    const float* g_f     = (const float*)d_in[13];
    const float* bt_f    = (const float*)d_in[14];
    const float* g_h     = (const float*)d_in[15];
    const float* bt_h    = (const float*)d_in[16];
    const float* W_h1    = (const float*)d_in[17];
    const float* b_h1    = (const float*)d_in[18];
    const float* W_h2    = (const float*)d_in[19];
    const float* b_h2    = (const float*)d_in[20];

    float* ws  = (float*)d_ws;
    float* H   = ws;                 // [BN][64]
    float* HA  = ws + 2097152;       // ping
    float* HB  = ws + 4194304;       // pong
    float* ACC = ws + 6291456;
    float* CAS = ws + 8388608;       // [64][4]
    float* CAD = ws + 8388864;
    float* CCE = ws + 8389120;       // [4][3]
    unsigned short* AsAdT = (unsigned short*)(ws + 8389376);  // [16][64]
    unsigned short* WT2h  = (unsigned short*)(ws + 8389888);  // [64][256]
    unsigned short* WT2l  = (unsigned short*)(ws + 8398080);  // [64][256]
    float* out = (float*)d_out;

    prep_kernel<<<1, 256, 0, stream>>>(W_gat, att_src, att_dst, W_edge, att_edge,
                                       CAS, CAD, CCE, AsAdT, WT2h, WT2l);
    enc_kernel<<<512, 256, 0, stream>>>(x, W_enc1, b_enc1, W_enc2, b_enc2, H, HA);

    float* hin = HA; float* hout = HB;
    for (int step = 0; step < 4; step++){
        for (int st = 0; st < 4; st++){
            f_kernel<<<512, 256, 0, stream>>>(hin, x, CCE, AsAdT, WT2h, WT2l,
                                              b_gat, g_f, bt_f,
                                              H, hout, ACC, st);
            float* tm = hin; hin = hout; hout = tm;
        }
    }

    head_kernel<<<512, 256, 0, stream>>>(H, x, g_h, bt_h, W_h1, b_h1, W_h2, b_h2, out);
}

// Round 7
// 512.645 us; speedup vs baseline: 1.0806x; 1.0806x over previous
//
#include <hip/hip_runtime.h>

#define NN 4096
#define BN 32768

typedef __attribute__((ext_vector_type(8))) short short8;
typedef __attribute__((ext_vector_type(4))) float f32x4;

__device__ __forceinline__ float sigmoidf_(float x){ return 1.f/(1.f+__expf(-x)); }
__device__ __forceinline__ unsigned short bfr(float f){
    unsigned int u = __float_as_uint(f);
    u += 0x7FFFu + ((u>>16)&1u);
    return (unsigned short)(u>>16);
}
__device__ __forceinline__ float b2f(unsigned short h){
    return __uint_as_float(((unsigned int)h)<<16);
}

// ---- prep: As/Ad, cE, AsAdT[16][64] bf16, WT2 hi/lo [64 j][256 khh] bf16 ----
__global__ void prep_kernel(const float* __restrict__ W_gat,
                            const float* __restrict__ att_src,
                            const float* __restrict__ att_dst,
                            const float* __restrict__ W_edge,
                            const float* __restrict__ att_edge,
                            float* __restrict__ As, float* __restrict__ Ad,
                            float* __restrict__ cE,
                            unsigned short* __restrict__ AsAdT,
                            unsigned short* __restrict__ WT2h,
                            unsigned short* __restrict__ WT2l)
{
    int t = threadIdx.x;          // 256
    int i = t >> 2, hh = t & 3;   // t = k*4+h
    float s = 0.f, d = 0.f;
    for (int j = 0; j < 64; j++){
        float w = W_gat[i*256 + hh*64 + j];
        s += w * att_src[hh*64 + j];
        d += w * att_dst[hh*64 + j];
    }
    As[t] = s;
    Ad[t] = d;
    if (t < 12){
        int e = t >> 2, h2 = t & 3;
        float cc = 0.f;
        for (int k = 0; k < 64; k++)
            cc += W_edge[e*256 + h2*64 + k] * att_edge[h2*64 + k];
        cE[h2*3 + e] = cc;
    }
    __syncthreads();
    if (t < 16){
        for (int k = 0; k < 64; k++){
            float v = (t < 4) ? As[k*4 + t] : (t < 8 ? Ad[k*4 + (t-4)] : 0.f);
            AsAdT[t*64 + k] = bfr(v);
        }
    }
    {
        int j = t >> 2, q = t & 3;
        for (int k = 0; k < 64; k++){
            float wv = W_gat[k*256 + q*64 + j];
            unsigned short hi = bfr(wv);
            WT2h[j*256 + q*64 + k] = hi;
            WT2l[j*256 + q*64 + k] = bfr(wv - b2f(hi));
        }
    }
}

// ---- encoder: block = 64 consecutive nodes, lane = node; node-major H + HA ----
__global__ __launch_bounds__(256) void enc_kernel(
    const float* __restrict__ x,
    const float* __restrict__ W1, const float* __restrict__ b1,
    const float* __restrict__ W2, const float* __restrict__ b2,
    float* __restrict__ H, float* __restrict__ HA)
{
    __shared__ __align__(16) float sm[5168];
    float* xT  = sm;          // [12][68]
    float* t1  = sm + 816;    // [64][68]

    int t = threadIdx.x;
    int w = __builtin_amdgcn_readfirstlane(t >> 6);
    int lane = t & 63;
    int n0 = blockIdx.x * 64;
    int b = n0 >> 12;
    int cell0 = n0 & 4095;

    for (int e = t; e < 12*64; e += 256){
        int c = e >> 6, u = e & 63;
        xT[c*68 + u] = x[b*(12*NN) + c*NN + cell0 + u];
    }
    __syncthreads();

    #pragma unroll
    for (int jj = 0; jj < 16; jj++){
        int j = w*16 + jj;
        float a = b1[j];
        #pragma unroll
        for (int c = 0; c < 12; c++)
            a += xT[c*68 + lane] * W1[c*64 + j];
        t1[j*68 + lane] = a * sigmoidf_(a);
    }
    __syncthreads();

    float hk[16];
    #pragma unroll
    for (int kk = 0; kk < 16; kk++) hk[kk] = b2[w*16 + kk];
    for (int j = 0; j < 64; j++){
        float v = t1[j*68 + lane];
        #pragma unroll
        for (int kk = 0; kk < 16; kk++)
            hk[kk] += v * W2[j*64 + w*16 + kk];
    }
    int hb = (n0 + lane)*64 + w*16;
    #pragma unroll
    for (int j4 = 0; j4 < 4; j4++){
        float4 v = make_float4(hk[4*j4+0], hk[4*j4+1], hk[4*j4+2], hk[4*j4+3]);
        *(float4*)&H[hb + 4*j4]  = v;
        *(float4*)&HA[hb + 4*j4] = v;
    }
}

// ================== f(): one RK4 stage, VALU mix -> MFMA GEMM ==================
// block = 8x8 tile + halo-1 (10x10); 4 waves; 3 barriers; 29.4KB LDS.
__global__ __launch_bounds__(256) void f_kernel(
    const float* __restrict__ HINc,        // stage input [BN][64] f32
    const float* __restrict__ x,
    const float* __restrict__ CCE,
    const unsigned short* __restrict__ AsAdT,
    const unsigned short* __restrict__ WT2h, const unsigned short* __restrict__ WT2l,
    const float* __restrict__ b_gat, const float* __restrict__ g_f, const float* __restrict__ bt_f,
    float* __restrict__ H, float* __restrict__ HOUT, float* __restrict__ ACC,
    int stage)
{
    __shared__ __align__(16) char smem[29376];
    unsigned short* hA = (unsigned short*)smem;          // [112][72] bf16 node-major
    float* aL  = (float*)(smem + 16128);                 // [64 e][36] f32: [e][o*4+h]
    float* as2 = (float*)(smem + 25344);                 // [112][4]
    float* ad2 = (float*)(smem + 27136);                 // [112][4]
    float* x0h = (float*)(smem + 28928);                 // [112]

    int t = threadIdx.x;
    int w = __builtin_amdgcn_readfirstlane(t >> 6);
    int lane = t & 63;
    int l15 = lane & 15, lg = lane >> 4;
    int blk = blockIdx.x;
    int b = blk & 7, tile = blk >> 3;      // batch pinned to XCD
    int tr = tile >> 3, tc = tile & 7;
    int r0 = tr*8 - 1, c0 = tc*8 - 1;
    int nb = b*NN;
    int xb = b*(12*NN);

    const int DYI[8] = {-1,-1,-1,0,0,1,1,1};
    const int DXI[8] = {-1,0,1,-1,1,-1,0,1};
    const float s2c = 0.70710678f;
    const float DXN[8] = {-s2c,0.f,s2c,-1.f,1.f,-s2c,0.f,s2c};
    const float DYN[8] = {-s2c,-1.f,-s2c,0.f,0.f,s2c,1.f,s2c};

    // ---- phase 1: stage halo (bf16) + x0; zero pad rows 100..111 ----
    for (int u = t; u < 432; u += 256)
        ((unsigned int*)(smem + 14400))[u] = 0u;
    for (int u = t; u < 1600; u += 256){
        int m = u >> 4, k4 = u & 15;
        int hr = m/10, hc = m - hr*10;
        int r = min(63,max(0,r0+hr)), c = min(63,max(0,c0+hc));
        float4 v = *(const float4*)&HINc[(long)(nb + r*64 + c)*64 + k4*4];
        unsigned int p0 = (unsigned int)bfr(v.x) | ((unsigned int)bfr(v.y)<<16);
        unsigned int p1 = (unsigned int)bfr(v.z) | ((unsigned int)bfr(v.w)<<16);
        *(uint2*)&hA[m*72 + k4*4] = make_uint2(p0,p1);
        if (k4 == 0) x0h[m] = x[xb + r*64 + c];
    }
    __syncthreads();

    // ---- phase 2: as/ad via MFMA (A = AsAdT, B = halo h from LDS) ----
    for (int nt = w; nt < 7; nt += 4){
        f32x4 acc = {0.f,0.f,0.f,0.f};
        #pragma unroll
        for (int kt = 0; kt < 2; kt++){
            short8 afr  = *(const short8*)&AsAdT[l15*64 + kt*32 + lg*8];
            short8 bfrg = *(const short8*)&hA[(nt*16+l15)*72 + kt*32 + lg*8];
            acc = __builtin_amdgcn_mfma_f32_16x16x32_bf16(afr, bfrg, acc, 0,0,0);
        }
        int m = nt*16 + l15;
        if (lg == 0)      *(float4*)&as2[m*4] = make_float4(acc[0],acc[1],acc[2],acc[3]);
        else if (lg == 1) *(float4*)&ad2[m*4] = make_float4(acc[0],acc[1],acc[2],acc[3]);
    }
    __syncthreads();

    // ---- phase 3: alpha per (e = lane, head = w) -> aL[e][o*4+h] ----
    {
        int e = lane;
        int er = e >> 3, ec = e & 7;
        int gr = tr*8 + er, gc = tc*8 + ec;
        int me = (er+1)*10 + (ec+1);
        float adv = ad2[me*4 + w];
        float x0n = x0h[me];
        float ce0 = CCE[w*3+0], ce1 = CCE[w*3+1], ce2 = CCE[w*3+2];
        float al[8]; float mx = -1e30f;
        #pragma unroll
        for (int o = 0; o < 8; o++){
            int mr = gr - DYI[o], mc = gc - DXI[o];
            bool vld = (mr>=0)&&(mr<64)&&(mc>=0)&&(mc<64);
            int hm = me - DYI[o]*10 - DXI[o];
            float a = as2[hm*4+w] + adv + ce0*DXN[o] + ce1*DYN[o]
                    + ce2*(x0n - x0h[hm]);
            a = (a >= 0.f) ? a : 0.2f*a;
            al[o] = vld ? a : -1e30f;
            mx = fmaxf(mx, al[o]);
        }
        float z = 0.f;
        #pragma unroll
        for (int o = 0; o < 8; o++){
            float p = (al[o] > -1e29f) ? __expf(al[o]-mx) : 0.f;
            al[o] = p; z += p;
        }
        float zi = 1.f/(z + 1e-16f);
        #pragma unroll
        for (int o = 0; o < 8; o++)
            aL[e*36 + o*4 + w] = al[o]*zi;
    }
    __syncthreads();

    // ---- phase 4: per-lane VALU mix straight into A-fragment layout ----
    // lane owns row e2 = w*16+l15, k-slice lg*8..+7; G[kt][i] = G[e2][kt*32+lg*8+i]
    int e2 = w*16 + l15;
    int er2 = e2 >> 3, ec2 = e2 & 7;
    int me2 = (er2+1)*10 + (ec2+1);
    float G[8][8];
    #pragma unroll
    for (int kt = 0; kt < 8; kt++)
        #pragma unroll
        for (int i = 0; i < 8; i++) G[kt][i] = 0.f;
    #pragma unroll
    for (int o = 0; o < 8; o++){
        int hm = me2 - DYI[o]*10 - DXI[o];
        float4 ao = *(const float4*)&aL[e2*36 + o*4];   // alpha for heads 0..3
        const unsigned short* hp = &hA[hm*72 + lg*8];
        short8 v0 = *(const short8*)&hp[0];             // k = lg*8+i
        short8 v1 = *(const short8*)&hp[32];            // k = 32+lg*8+i
        #pragma unroll
        for (int i = 0; i < 8; i++){
            float f0 = b2f((unsigned short)v0[i]);
            float f1 = b2f((unsigned short)v1[i]);
            G[0][i] += ao.x*f0;  G[1][i] += ao.x*f1;
            G[2][i] += ao.y*f0;  G[3][i] += ao.y*f1;
            G[4][i] += ao.z*f0;  G[5][i] += ao.z*f1;
            G[6][i] += ao.w*f0;  G[7][i] += ao.w*f1;
        }
    }

    // ---- phase 5: stacked GEMM out[e][j] = G @ WT2 (hi+lo), A from regs ----
    f32x4 oacc[4];
    #pragma unroll
    for (int nt = 0; nt < 4; nt++) oacc[nt] = (f32x4){0.f,0.f,0.f,0.f};
    #pragma unroll
    for (int kt = 0; kt < 8; kt++){
        short8 afr;
        #pragma unroll
        for (int i = 0; i < 8; i++) afr[i] = (short)bfr(G[kt][i]);
        #pragma unroll
        for (int nt = 0; nt < 4; nt++){
            short8 bh = *(const short8*)&WT2h[(nt*16+l15)*256 + kt*32 + lg*8];
            oacc[nt] = __builtin_amdgcn_mfma_f32_16x16x32_bf16(afr, bh, oacc[nt], 0,0,0);
        }
        #pragma unroll
        for (int nt = 0; nt < 4; nt++){
            short8 bl = *(const short8*)&WT2l[(nt*16+l15)*256 + kt*32 + lg*8];
            oacc[nt] = __builtin_amdgcn_mfma_f32_16x16x32_bf16(afr, bl, oacc[nt], 0,0,0);
        }
    }

    // ---- phase 6: epilogue: LN (16-lane shfl) + silu + RK4 ----
    float bg[4], gf[4], bf_[4];
    #pragma unroll
    for (int nt = 0; nt < 4; nt++){
        int j = nt*16 + l15;
        bg[nt] = b_gat[j]; gf[nt] = g_f[j]; bf_[nt] = bt_f[j];
    }
    #pragma unroll
    for (int reg = 0; reg < 4; reg++){
        int e3 = w*16 + lg*4 + reg;
        float vv[4];
        float s1 = 0.f, s2 = 0.f;
        #pragma unroll
        for (int nt = 0; nt < 4; nt++){
            float v = oacc[nt][reg]*0.25f + bg[nt];
            vv[nt] = v; s1 += v; s2 += v*v;
        }
        s1 += __shfl_xor(s1,1); s2 += __shfl_xor(s2,1);
        s1 += __shfl_xor(s1,2); s2 += __shfl_xor(s2,2);
        s1 += __shfl_xor(s1,4); s2 += __shfl_xor(s2,4);
        s1 += __shfl_xor(s1,8); s2 += __shfl_xor(s2,8);
        float mean = s1*(1.f/64.f);
        float var  = s2*(1.f/64.f) - mean*mean;
        float rstd = rsqrtf(fmaxf(var,0.f) + 1e-5f);
        int r2 = e3 >> 3, c2 = e3 & 7;
        long gn = nb + (tr*8 + r2)*64 + (tc*8 + c2);
        #pragma unroll
        for (int nt = 0; nt < 4; nt++){
            int j = nt*16 + l15;
            float y = (vv[nt]-mean)*rstd*gf[nt] + bf_[nt];
            float kv = y * sigmoidf_(y);
            long idx = gn*64 + j;
            float hold = H[idx];
            float hn;
            if (stage == 0){
                ACC[idx] = kv;                 hn = hold + 0.125f*kv;
            } else if (stage == 1){
                ACC[idx] += 2.f*kv;            hn = hold + 0.125f*kv;
            } else if (stage == 2){
                ACC[idx] += 2.f*kv;            hn = hold + 0.25f*kv;
            } else {
                hn = hold + (0.25f/6.f)*(ACC[idx] + kv);
                H[idx] = hn;
            }
            HOUT[idx] = hn;
        }
    }
}

// ---- head: LN + MLP + fire override ----
__global__ __launch_bounds__(256) void head_kernel(
    const float* __restrict__ H, const float* __restrict__ x,
    const float* __restrict__ g_h, const float* __restrict__ bt_h,
    const float* __restrict__ Wh1, const float* __restrict__ bh1,
    const float* __restrict__ Wh2, const float* __restrict__ bh2,
    float* __restrict__ out)
{
    __shared__ __align__(16) float sm[4624];
    float* hT = sm;          // [64][68]
    float* pl = sm + 4352;   // [4][68]

    int t = threadIdx.x;
    int w = __builtin_amdgcn_readfirstlane(t >> 6);
    int lane = t & 63;
    int n0 = blockIdx.x * 64;
    int b = n0 >> 12;
    int cell0 = n0 & 4095;

    for (int e = t; e < 4096; e += 256){
        int n = e >> 6, j = e & 63;
        hT[j*68 + n] = H[(n0+n)*64 + j];
    }
    __syncthreads();

    float s1 = 0.f, s2 = 0.f;
    for (int j = 0; j < 64; j++){
        float v = hT[j*68 + lane];
        s1 += v; s2 += v*v;
    }
    float mean = s1*(1.f/64.f);
    float var  = s2*(1.f/64.f) - mean*mean;
    float rstd = rsqrtf(fmaxf(var, 0.f) + 1e-5f);

    float acc[16];
    #pragma unroll
    for (int kk = 0; kk < 16; kk++) acc[kk] = bh1[w*16 + kk];
    for (int j = 0; j < 64; j++){
        float v = (hT[j*68 + lane] - mean)*rstd*g_h[j] + bt_h[j];
        #pragma unroll
        for (int kk = 0; kk < 16; kk++)
            acc[kk] += v * Wh1[j*64 + w*16 + kk];
    }
    float plg = 0.f;
    #pragma unroll
    for (int kk = 0; kk < 16; kk++){
        float a = acc[kk];
        plg += (a * sigmoidf_(a)) * Wh2[w*16 + kk];
    }
    pl[w*68 + lane] = plg;
    __syncthreads();
    if (t < 64){
        float lgt = pl[0*68+t] + pl[1*68+t] + pl[2*68+t] + pl[3*68+t] + bh2[0];
        float fire = x[b*(12*NN) + cell0 + t];
        out[n0 + t] = (fire > 0.5f) ? fmaxf(lgt, 6.f) : lgt;
    }
}

extern "C" void kernel_launch(void* const* d_in, const int* in_sizes, int n_in,
                              void* d_out, int out_size, void* d_ws, size_t ws_size,
                              hipStream_t stream)
{
    const float* x       = (const float*)d_in[0];
    const float* W_enc1  = (const float*)d_in[3];
    const float* b_enc1  = (const float*)d_in[4];
    const float* W_enc2  = (const float*)d_in[5];
    const float* b_enc2  = (const float*)d_in[6];
    const float* W_gat   = (const float*)d_in[7];
    const float* att_src = (const float*)d_in[8];
    const float* att_dst = (const float*)d_in[9];
    const float* W_edge  = (const float*)d_in[10];
    const float* att_edge= (const float*)d_in[11];
    const float* b_gat   = (const float*)d_in[12];
    const float* g_f     = (const float*)d_in[13];
    const float* bt_f    = (const float*)d_in[14];
    const float* g_h     = (const float*)d_in[15];
    const float* bt_h    = (const float*)d_in[16];
    const float* W_h1    = (const float*)d_in[17];
    const float* b_h1    = (const float*)d_in[18];
    const float* W_h2    = (const float*)d_in[19];
    const float* b_h2    = (const float*)d_in[20];

    float* ws  = (float*)d_ws;
    float* H   = ws;                 // [BN][64]
    float* HA  = ws + 2097152;       // ping
    float* HB  = ws + 4194304;       // pong
    float* ACC = ws + 6291456;
    float* CAS = ws + 8388608;       // [64][4]
    float* CAD = ws + 8388864;
    float* CCE = ws + 8389120;       // [4][3]
    unsigned short* AsAdT = (unsigned short*)(ws + 8389376);  // [16][64]
    unsigned short* WT2h  = (unsigned short*)(ws + 8389888);  // [64][256]
    unsigned short* WT2l  = (unsigned short*)(ws + 8398080);  // [64][256]
    float* out = (float*)d_out;

    prep_kernel<<<1, 256, 0, stream>>>(W_gat, att_src, att_dst, W_edge, att_edge,
                                       CAS, CAD, CCE, AsAdT, WT2h, WT2l);
    enc_kernel<<<512, 256, 0, stream>>>(x, W_enc1, b_enc1, W_enc2, b_enc2, H, HA);

    float* hin = HA; float* hout = HB;
    for (int step = 0; step < 4; step++){
        for (int st = 0; st < 4; st++){
            f_kernel<<<512, 256, 0, stream>>>(hin, x, CCE, AsAdT, WT2h, WT2l,
                                              b_gat, g_f, bt_f,
                                              H, hout, ACC, st);
            float* tm = hin; hin = hout; hout = tm;
        }
    }

    head_kernel<<<512, 256, 0, stream>>>(H, x, g_h, bt_h, W_h1, b_h1, W_h2, b_h2, out);
}